// Round 12
// baseline (64.202 us; speedup 1.0000x reference)
//
#include <hip/hip_runtime.h>
#include <hip/hip_bf16.h>

typedef unsigned short u16;
typedef unsigned int u32;
typedef float f32x4 __attribute__((ext_vector_type(4)));
typedef float f32x16 __attribute__((ext_vector_type(16)));
typedef short s16x8 __attribute__((ext_vector_type(8)));

#define MFMA32(a,b,c) __builtin_amdgcn_mfma_f32_32x32x16_bf16((a),(b),(c),0,0,0)
#define MFMA16(a,b,c) __builtin_amdgcn_mfma_f32_16x16x32_bf16((a),(b),(c),0,0,0)

static __device__ __forceinline__ u16 f2bf(float x){
  union { __hip_bfloat16 b; u16 u; } c;
  c.b = __float2bfloat16(x);
  return c.u;
}
static __device__ __forceinline__ u32 pk2(float a, float b){
  return (u32)f2bf(a) | ((u32)f2bf(b) << 16);
}

// lgkm-only barrier (keeps global loads in flight across barriers)
static __device__ __forceinline__ void softbar() {
  __builtin_amdgcn_sched_barrier(0);
  asm volatile("s_waitcnt lgkmcnt(0)" ::: "memory");
  __builtin_amdgcn_s_barrier();
  __builtin_amdgcn_sched_barrier(0);
}

// ---------------------------------------------------------------------------
// prep: bf16 transposed weights + gin[:,0:512]. Now also Wg2T (for fused
// gate+finalize). Grid 3456 (884736 elements).
// ---------------------------------------------------------------------------
__global__ void prep_kernel(const float* __restrict__ Wm1, const float* __restrict__ Wm2,
                            const float* __restrict__ Wm3, const float* __restrict__ Wg1,
                            const float* __restrict__ Wr,  const float* __restrict__ Wt1,
                            const float* __restrict__ Wg2,
                            const float* __restrict__ node,const float* __restrict__ prev,
                            const float* __restrict__ edge,const float* __restrict__ graph,
                            u16* __restrict__ WbT, u16* __restrict__ WgrT,
                            u16* __restrict__ Wm2T, u16* __restrict__ Wm3T,
                            u16* __restrict__ Wg2T, u16* __restrict__ gin)
{
  int idx = blockIdx.x * 256 + threadIdx.x;
  if (idx < 147456) {                       // WbT: 288*512
    int n = idx >> 9, k = idx & 511;
    int part = k >> 7, kk = k & 127;
    float v = 0.f;
    if (n < 128) {                          // u = z@W_zi + gb@W_g
      if (part == 0)      v = Wm1[kk*128 + n];
      else if (part == 1) v = Wm1[(128+kk)*128 + n];
      else if (part == 3) v = Wm1[(640+kk)*128 + n];
    } else if (n < 256) {                   // v = z@W_zj + edge@W_e
      int nn = n - 128;
      if (part == 0)      v = Wm1[(256+kk)*128 + nn];
      else if (part == 1) v = Wm1[(384+kk)*128 + nn];
      else if (part == 2) v = Wm1[(512+kk)*128 + nn];
    } else if (n < 280) {                   // a_j(8) a_k(8) c(8)
      int tt = n - 256;
      if (tt < 8)       { if (part == 0) v = Wt1[kk*8 + tt]; }
      else if (tt < 16) { if (part == 0) v = Wt1[(128+kk)*8 + (tt-8)]; }
      else {
        int t = tt - 16;
        if (part == 0)      v = Wt1[(256+kk)*8 + t];
        else if (part == 2) v = Wt1[(384+kk)*8 + t] + Wt1[(512+kk)*8 + t] + Wt1[(640+kk)*8 + t];
        else if (part == 3) v = Wt1[(768+kk)*8 + t];
      }
    }
    WbT[idx] = f2bf(v);
    return;
  }
  idx -= 147456;
  if (idx < 163840) {                       // WgrT: 256*640
    int n = idx / 640, k = idx - n*640;
    int part = k >> 7, kk = k & 127;
    float v = 0.f;
    if (n < 128) {
      int r = (part==0) ? kk : (part==1) ? (128+kk) : (part==2) ? (384+kk)
                        : (part==3) ? (512+kk) : (256+kk);
      v = Wg1[r*128 + n];
    } else {
      int nn = n - 128;
      if (part == 0)      v = Wr[kk*128 + nn];
      else if (part == 1) v = Wr[(128+kk)*128 + nn];
      else if (part == 4) v = Wr[(256+kk)*128 + nn];
    }
    WgrT[idx] = f2bf(v);
    return;
  }
  idx -= 163840;
  if (idx < 16384) { int n = idx >> 7, k = idx & 127; Wm2T[idx] = f2bf(Wm2[k*128 + n]); return; }
  idx -= 16384;
  if (idx < 16384) { int n = idx >> 7, k = idx & 127; Wm3T[idx] = f2bf(Wm3[k*128 + n]); return; }
  idx -= 16384;
  if (idx < 16384) { int n = idx >> 7, k = idx & 127; Wg2T[idx] = f2bf(Wg2[k*128 + n]); return; }
  idx -= 16384;
  {                                         // gin cols 0:512
    int row = idx >> 9, k = idx & 511;
    int part = k >> 7, kk = k & 127;
    float v;
    if (part == 0)      v = node[row*128 + kk];
    else if (part == 1) v = prev[row*128 + kk];
    else if (part == 2) v = edge[row*128 + kk];
    else                v = graph[(row >> 8)*128 + kk];
    gin[row*640 + k] = f2bf(v);
  }
}

// ---------------------------------------------------------------------------
// G1: uvt[1024][288] = gin[:,0:512] @ WbT^T  (K split across 4 waves)
// ---------------------------------------------------------------------------
__global__ __launch_bounds__(256) void gemm_uvt_kernel(const u16* __restrict__ gin,
                                                       const u16* __restrict__ WbT,
                                                       float* __restrict__ uvt)
{
  int m0 = blockIdx.x * 16, n0 = blockIdx.y * 16;
  int tid = threadIdx.x;
  int w = tid >> 6, lane = tid & 63;
  int c = lane & 15, g = lane >> 4;
  __shared__ float cpart[4][16][17];
  const u16* arow = gin + (size_t)(m0 + c) * 640;
  const u16* brow = WbT + (size_t)(n0 + c) * 512;
  f32x4 acc = {0.f, 0.f, 0.f, 0.f};
#pragma unroll
  for (int kk = 0; kk < 4; ++kk) {
    int k0 = w*4 + kk;
    s16x8 a = *reinterpret_cast<const s16x8*>(arow + k0*32 + g*8);
    s16x8 b = *reinterpret_cast<const s16x8*>(brow + k0*32 + g*8);
    acc = MFMA16(a, b, acc);
  }
#pragma unroll
  for (int r = 0; r < 4; ++r) cpart[w][g*4 + r][c] = acc[r];
  __syncthreads();
  int row = tid >> 4, col = tid & 15;
  float s = cpart[0][row][col] + cpart[1][row][col]
          + cpart[2][row][col] + cpart[3][row][col];
  uvt[(size_t)(m0 + row) * 288 + n0 + col] = s;
}

// ---------------------------------------------------------------------------
// msgmax v12: v11 (32x32 MFMA) + i-batch x2. Block = rows {2bx, 2bx+1} (same
// batch -> shared v panel). 512 blocks, 4 waves; wave owns 32 output cols.
// Per iter (32 j): build a1 for BOTH i from one vc load; softbar; GEMM1 x2
// (16 MFMA, independent chains); h2 x2 -> LDS; softbar; GEMM2 x2 + max.
// Fixed costs (weights, prologue) amortize over 2x work; ~200 VGPR ->
// 8 waves/CU -> both blocks/CU resident (single dispatch round).
// ---------------------------------------------------------------------------
__global__ __launch_bounds__(256) void msgmax_kernel(const float* __restrict__ uvt,
    const u16* __restrict__ Wm2T, const u16* __restrict__ Wm3T,
    const float* __restrict__ bm1, const float* __restrict__ bm2,
    const float* __restrict__ bm3, u16* __restrict__ gin, float* __restrict__ mjk)
{
  const int bx   = blockIdx.x;
  const int row0 = bx * 2;
  const int b    = row0 >> 8;
  const int tid = threadIdx.x;
  const int w   = tid >> 6;
  const int lane = tid & 63;
  const int jc = lane & 31;        // A-row / B-col / C-col lane index
  const int hi = lane >> 5;        // k-octet selector
  const int colbase = w * 32;

  __shared__ u16 a1s[2][32][136];  // [i][j][k 128 + 8 pad]
  __shared__ u16 h2s[2][32][136];
  __shared__ float part[4][16];

  s16x8 wb2[8], wb3[8];
#pragma unroll
  for (int ks = 0; ks < 8; ++ks) {
    wb2[ks] = *reinterpret_cast<const s16x8*>(Wm2T + (colbase + jc)*128 + ks*16 + hi*8);
    wb3[ks] = *reinterpret_cast<const s16x8*>(Wm3T + (colbase + jc)*128 + ks*16 + hi*8);
  }

  const int bj = lane >> 3;
  const int bk = (lane & 7) * 16;
  f32x4 uf[2][4];
#pragma unroll
  for (int i = 0; i < 2; ++i) {
    const float* urow = uvt + (size_t)(row0 + i) * 288;
#pragma unroll
    for (int q = 0; q < 4; ++q)
      uf[i][q] = *reinterpret_cast<const f32x4*>(urow + bk + q*4)
               + *reinterpret_cast<const f32x4*>(bm1 + bk + q*4);
  }
  f32x4 bm2v[4];
#pragma unroll
  for (int grp = 0; grp < 4; ++grp)
    bm2v[grp] = *reinterpret_cast<const f32x4*>(bm2 + colbase + grp*8 + 4*hi);

  const f32x4 z4 = {0.f, 0.f, 0.f, 0.f};
  float mm[2][16];
#pragma unroll
  for (int i = 0; i < 2; ++i)
#pragma unroll
    for (int t = 0; t < 16; ++t) mm[i][t] = -1e30f;

  const float* vb = uvt + (size_t)(b*256) * 288 + 128;
  f32x4 vc[4];
#define LOADV(IT) do { \
  const float* p_ = vb + (size_t)((IT)*32 + w*8 + bj) * 288 + bk; \
  vc[0] = *reinterpret_cast<const f32x4*>(p_); \
  vc[1] = *reinterpret_cast<const f32x4*>(p_ + 4); \
  vc[2] = *reinterpret_cast<const f32x4*>(p_ + 8); \
  vc[3] = *reinterpret_cast<const f32x4*>(p_ + 12); } while (0)

  LOADV(0);

  for (int it = 0; it < 8; ++it) {
    // ---- build a1 rows [8w,8w+8) for BOTH i from the shared v slice ----
#pragma unroll
    for (int i = 0; i < 2; ++i) {
#pragma unroll
      for (int q = 0; q < 2; ++q) {
        f32x4 lo = __builtin_elementwise_max(vc[2*q]   + uf[i][2*q],   z4);
        f32x4 hn = __builtin_elementwise_max(vc[2*q+1] + uf[i][2*q+1], z4);
        uint4 pk = {pk2(lo[0], lo[1]), pk2(lo[2], lo[3]),
                    pk2(hn[0], hn[1]), pk2(hn[2], hn[3])};
        *reinterpret_cast<uint4*>(&a1s[i][w*8 + bj][bk + q*8]) = pk;
      }
    }
    if (it < 7) LOADV(it + 1);
    softbar();                       // a1 ready

#pragma unroll
    for (int i = 0; i < 2; ++i) {
      f32x16 acc1;
#pragma unroll
      for (int grp = 0; grp < 4; ++grp)
#pragma unroll
        for (int r = 0; r < 4; ++r) acc1[grp*4 + r] = bm2v[grp][r];
#pragma unroll
      for (int ks = 0; ks < 8; ++ks) {
        s16x8 bf = *reinterpret_cast<const s16x8*>(&a1s[i][jc][ks*16 + hi*8]);
        acc1 = MFMA32(wb2[ks], bf, acc1);
      }
#pragma unroll
      for (int grp = 0; grp < 4; ++grp) {
        float v0 = fmaxf(acc1[grp*4+0], 0.f), v1 = fmaxf(acc1[grp*4+1], 0.f);
        float v2 = fmaxf(acc1[grp*4+2], 0.f), v3 = fmaxf(acc1[grp*4+3], 0.f);
        uint2 pk = {pk2(v0, v1), pk2(v2, v3)};
        *reinterpret_cast<uint2*>(&h2s[i][jc][colbase + grp*8 + 4*hi]) = pk;
      }
    }
    softbar();                       // h2 ready

#pragma unroll
    for (int i = 0; i < 2; ++i) {
      f32x16 acc2 = {0.f,0.f,0.f,0.f,0.f,0.f,0.f,0.f,
                     0.f,0.f,0.f,0.f,0.f,0.f,0.f,0.f};
#pragma unroll
      for (int ks = 0; ks < 8; ++ks) {
        s16x8 bf = *reinterpret_cast<const s16x8*>(&h2s[i][jc][ks*16 + hi*8]);
        acc2 = MFMA32(wb3[ks], bf, acc2);
      }
#pragma unroll
      for (int t = 0; t < 16; ++t) mm[i][t] = fmaxf(mm[i][t], acc2[t]);
    }
  }
#undef LOADV

  // reduce max over j lanes; fold bm3; write m rows
#pragma unroll
  for (int i = 0; i < 2; ++i) {
#pragma unroll
    for (int t = 0; t < 16; ++t) {
      mm[i][t] = fmaxf(mm[i][t], __shfl_xor(mm[i][t], 1));
      mm[i][t] = fmaxf(mm[i][t], __shfl_xor(mm[i][t], 2));
      mm[i][t] = fmaxf(mm[i][t], __shfl_xor(mm[i][t], 4));
      mm[i][t] = fmaxf(mm[i][t], __shfl_xor(mm[i][t], 8));
      mm[i][t] = fmaxf(mm[i][t], __shfl_xor(mm[i][t], 16));
    }
    if (jc == 0) {
#pragma unroll
      for (int grp = 0; grp < 4; ++grp) {
        int col = colbase + grp*8 + 4*hi;
        uint2 pk = {pk2(mm[i][grp*4+0] + bm3[col],   mm[i][grp*4+1] + bm3[col+1]),
                    pk2(mm[i][grp*4+2] + bm3[col+2], mm[i][grp*4+3] + bm3[col+3])};
        *reinterpret_cast<uint2*>(gin + (size_t)(row0 + i)*640 + 512 + col) = pk;
      }
    }
  }

  // ---- folded maxat: blocks 0..3 compute per-batch max of a_j,a_k ----
  if (bx < 4) {
    __syncthreads();
    int rr = bx*256 + tid;
    float v[16];
#pragma unroll
    for (int t = 0; t < 16; ++t) v[t] = uvt[(size_t)rr*288 + 256 + t];
#pragma unroll
    for (int off = 32; off >= 1; off >>= 1) {
#pragma unroll
      for (int t = 0; t < 16; ++t) v[t] = fmaxf(v[t], __shfl_xor(v[t], off));
    }
    int wid = tid >> 6;
    if ((tid & 63) == 0) {
#pragma unroll
      for (int t = 0; t < 16; ++t) part[wid][t] = v[t];
    }
    __syncthreads();
    if (tid < 16)
      mjk[bx*16 + tid] = fmaxf(fmaxf(part[0][tid], part[1][tid]),
                               fmaxf(part[2][tid], part[3][tid]));
  }
}

// ---------------------------------------------------------------------------
// gate_finalize (fused): block = 16 rows. Stage gin tile (16x640) in LDS,
// GEMM -> [r1|hi] (r1 -> bf16 LDS, hi -> f32 LDS), GEMM r1@Wg2T -> g_lin,
// then sigmoid/mix/layernorm/T-head per row. Saves a launch + r1/hi
// global round-trip.
// ---------------------------------------------------------------------------
__global__ __launch_bounds__(256) void gate_finalize_kernel(
    const u16* __restrict__ gin, const u16* __restrict__ WgrT,
    const u16* __restrict__ Wg2T,
    const float* __restrict__ bg1, const float* __restrict__ br,
    const float* __restrict__ bg2, const float* __restrict__ prev,
    const float* __restrict__ uvt, const float* __restrict__ mjk,
    const float* __restrict__ bt1, const float* __restrict__ Wt2,
    const float* __restrict__ bt2, const float* __restrict__ gamma,
    const float* __restrict__ beta, float* __restrict__ out)
{
  const int m0 = blockIdx.x * 16;
  const int tid = threadIdx.x;
  const int w = tid >> 6, lane = tid & 63;
  const int c = lane & 15, g = lane >> 4;

  __shared__ u16 at[16][648];     // gin tile (16x640 + pad)
  __shared__ u16 r1b[16][136];    // r1 bf16
  __shared__ float his[16][132];  // h_i f32
  __shared__ float gls[16][132];  // g_lin f32

  // stage A tile: 1280 x b128, 5 per thread
#pragma unroll
  for (int q = 0; q < 5; ++q) {
    int idx = q*256 + tid;
    int r = idx / 80, kk = (idx - r*80) * 8;
    *reinterpret_cast<uint4*>(&at[r][kk]) =
      *reinterpret_cast<const uint4*>(gin + (size_t)(m0 + r)*640 + kk);
  }
  __syncthreads();

  // phase 1: [r1|hi](16x256) = at @ WgrT^T, K=640; wave w -> cols [64w,64w+64)
#pragma unroll
  for (int nt = 0; nt < 4; ++nt) {
    int n0 = w*64 + nt*16;
    const u16* brow = WgrT + (size_t)(n0 + c) * 640;
    f32x4 acc = {0.f, 0.f, 0.f, 0.f};
#pragma unroll
    for (int k0 = 0; k0 < 20; ++k0) {
      s16x8 a = *reinterpret_cast<const s16x8*>(&at[c][k0*32 + g*8]);
      s16x8 b = *reinterpret_cast<const s16x8*>(brow + k0*32 + g*8);
      acc = MFMA16(a, b, acc);
    }
    int ocol = n0 + c;
#pragma unroll
    for (int r = 0; r < 4; ++r) {
      int orow = g*4 + r;
      if (ocol < 128) {
        float val = fmaxf(acc[r] + bg1[ocol], 0.f);
        r1b[orow][ocol] = f2bf(val);
      } else {
        his[orow][ocol - 128] = acc[r] + br[ocol - 128];
      }
    }
  }
  __syncthreads();

  // phase 2: g_lin(16x128) = r1b @ Wg2T^T, K=128; wave w -> cols [32w,32w+32)
#pragma unroll
  for (int nt = 0; nt < 2; ++nt) {
    int n0 = w*32 + nt*16;
    const u16* brow = Wg2T + (size_t)(n0 + c) * 128;
    f32x4 acc = {0.f, 0.f, 0.f, 0.f};
#pragma unroll
    for (int k0 = 0; k0 < 4; ++k0) {
      s16x8 a = *reinterpret_cast<const s16x8*>(&r1b[c][k0*32 + g*8]);
      s16x8 b = *reinterpret_cast<const s16x8*>(brow + k0*32 + g*8);
      acc = MFMA16(a, b, acc);
    }
    int ocol = n0 + c;
#pragma unroll
    for (int r = 0; r < 4; ++r)
      gls[g*4 + r][ocol] = acc[r] + bg2[ocol];
  }
  __syncthreads();

  // phase 3: per-row sigmoid/mix/layernorm + T-head. thread -> (row, 8 cols)
  const int row = tid >> 4;
  const int cb = (tid & 15) * 8;
  const int grow = m0 + row;
  const int bb = grow >> 8;
  const float* prow = prev + (size_t)grow * 128 + cb;

  float hgv[8];
  float s1 = 0.f, s2 = 0.f;
#pragma unroll
  for (int q = 0; q < 8; ++q) {
    float gl = gls[row][cb + q];
    float gg = 1.f / (1.f + __expf(-gl));
    float hg = gg * his[row][cb + q] + (1.f - gg) * prow[q];
    hgv[q] = hg; s1 += hg; s2 += hg*hg;
  }
#pragma unroll
  for (int off = 1; off < 16; off <<= 1) {
    s1 += __shfl_xor(s1, off);
    s2 += __shfl_xor(s2, off);
  }
  float mu  = s1 * 0.0078125f;
  float var = s2 * 0.0078125f - mu*mu;
  float rs  = rsqrtf(var + 1e-5f);
#pragma unroll
  for (int q = 0; q < 8; ++q) {
    int col = cb + q;
    out[(size_t)grow*128 + col] = (hgv[q] - mu) * rs * gamma[col] + beta[col];
  }

  // T-head: h_ij = relu(c + bt1 + maxaj + maxak) @ Wt2 + bt2
  float tv[8];
  const float* crow = uvt + (size_t)grow * 288 + 272;
#pragma unroll
  for (int t = 0; t < 8; ++t)
    tv[t] = fmaxf(crow[t] + bt1[t] + mjk[bb*16 + t] + mjk[bb*16 + 8 + t], 0.f);
#pragma unroll
  for (int q = 0; q < 8; ++q) {
    int col = cb + q;
    float o2 = bt2[col];
#pragma unroll
    for (int t = 0; t < 8; ++t) o2 += tv[t] * Wt2[t*128 + col];
    out[131072 + (size_t)grow*128 + col] = o2;
  }
}

// ---------------------------------------------------------------------------
extern "C" void kernel_launch(void* const* d_in, const int* in_sizes, int n_in,
                              void* d_out, int out_size, void* d_ws, size_t ws_size,
                              hipStream_t stream) {
  const float* node  = (const float*)d_in[0];
  const float* edge  = (const float*)d_in[1];
  const float* graph = (const float*)d_in[2];
  const float* prev  = (const float*)d_in[3];
  const float* Wm1 = (const float*)d_in[4];
  const float* bm1 = (const float*)d_in[5];
  const float* Wm2 = (const float*)d_in[6];
  const float* bm2 = (const float*)d_in[7];
  const float* Wm3 = (const float*)d_in[8];
  const float* bm3 = (const float*)d_in[9];
  const float* Wg1 = (const float*)d_in[10];
  const float* bg1 = (const float*)d_in[11];
  const float* Wg2 = (const float*)d_in[12];
  const float* bg2 = (const float*)d_in[13];
  const float* Wr  = (const float*)d_in[14];
  const float* br  = (const float*)d_in[15];
  const float* Wt1 = (const float*)d_in[16];
  const float* bt1 = (const float*)d_in[17];
  const float* Wt2 = (const float*)d_in[18];
  const float* bt2 = (const float*)d_in[19];
  const float* gamma = (const float*)d_in[20];
  const float* beta  = (const float*)d_in[21];
  float* out = (float*)d_out;

  char* ws = (char*)d_ws;
  u16*   WbT  = (u16*)(ws + 0);        // 288*512*2   = 294912
  u16*   WgrT = (u16*)(ws + 294912);   // 256*640*2   = 327680
  u16*   Wm2T = (u16*)(ws + 622592);   // 16384*2
  u16*   Wm3T = (u16*)(ws + 655360);   // 16384*2
  u16*   gin  = (u16*)(ws + 688128);   // 1024*640*2  = 1310720
  float* uvt  = (float*)(ws + 1998848);// 1024*288*4  = 1179648
  u16*   Wg2T = (u16*)(ws + 3178496);  // 16384*2     = 32768
  float* mjk  = (float*)(ws + 3211264);// 4*16*4      = 256

  prep_kernel<<<3456, 256, 0, stream>>>(Wm1, Wm2, Wm3, Wg1, Wr, Wt1, Wg2,
                                        node, prev, edge, graph,
                                        WbT, WgrT, Wm2T, Wm3T, Wg2T, gin);
  gemm_uvt_kernel<<<dim3(64, 18), 256, 0, stream>>>(gin, WbT, uvt);
  msgmax_kernel<<<512, 256, 0, stream>>>(uvt, Wm2T, Wm3T, bm1, bm2, bm3, gin, mjk);
  gate_finalize_kernel<<<64, 256, 0, stream>>>(gin, WgrT, Wg2T, bg1, br, bg2,
                                               prev, uvt, mjk, bt1, Wt2, bt2,
                                               gamma, beta, out);
}